// Round 12
// baseline (123.495 us; speedup 1.0000x reference)
//
#include <hip/hip_runtime.h>

// ClusterLoss fused kernel for MI355X (gfx950).  R18b (= R18 resubmitted;
// round 11 failure was container acquisition, not a kernel verdict; source
// re-audited for hang/crash paths: uniform barrier, LDS 133KB<160KB, all
// indices bounds-checked, layout re-verified).
// Cross-round post-mortem (R14 43us / R16 45us / R17 41us): delivered B-read
// bandwidth pinned at ~12 TB/s in all three (512 MB / dur) regardless of
// occupancy (17-46%) or depth-1 pipelining => pure-L2 bandwidth ceiling for
// the streamed fragment pattern (the 34.5 TB/s ubench includes L1 reuse we
// don't get). The sweep is B-BANDWIDTH-bound; TLP/latency changes are moot.
// R18 cuts B L2 traffic 8x: 8-wave 512-thread block stages ALL 128 KB of
// frag-ordered centers into LDS once (linear copy, conflict-free b128 at
// lane*16), ONE barrier, then each wave is fully autonomous (R14's verified
// math): own 32-row tile, sweeps all 1024 centers from LDS, in-wave keyed
// argmax + loss, per-wave wsum partial. No per-rt barriers, no atomics.
//   - B staging: 512 blocks x 128 KB = 64 MB from L2 (8x cut), ~5us overlapped.
//   - sweep B reads now LDS: ~16 B/cyc/SIMD vs 85 ceiling -> trivially fed.
//   - A fragments direct from global (R15-verified), feats read once (33 MB).
//   - LDS 130 KB -> 1 block/CU, 2 waves/SIMD; VGPR bracket irrelevant now.
// Allocator rules (measured): 512-thr + launch_bounds(512,1) -> ~100 VGPR,
// no spill. 1024-thr or min-waves>=2 pins 64 VGPR + spill. Tripwire=WRITE_SIZE.
// loss_n = 1 - 2 d na/nf + na^2 (fp32 scalars).

#define D 128

typedef __attribute__((ext_vector_type(4))) float floatx4;
typedef __attribute__((ext_vector_type(2))) long long llx2;

template <bool HI>
__device__ __forceinline__ unsigned int pk_fp8(float a, float b, unsigned int old) {
    return (unsigned int)__builtin_amdgcn_cvt_pk_fp8_f32(a, b, (int)old, HI);
}

__device__ __forceinline__ float key_pack(float v, unsigned int inv_k) {
    unsigned int u = __builtin_bit_cast(unsigned int, v);
    unsigned int r = (0x3FFu & inv_k) | (~0x3FFu & u);   // v_bfi_b32
    return __builtin_bit_cast(float, r);
}

// ---- Prep: normalize centers -> fp8 into LDS-linear frag order ----
// fragment (g, flane, kk) lives at (g*2 + (kk>>1))*1024 + flane*16 + (kk&1)*8
// so a wave's ds_read_b128 at (4*g2+j)*1024 + lane*16 is contiguous 1 KB.
__global__ void prep_centers(const float* __restrict__ centers,
                             unsigned char* __restrict__ bws2,
                             float* __restrict__ cnorm) {
    const int k = blockIdx.x;
    const int t = threadIdx.x;            // 128 threads, one per dim
    float v = centers[(size_t)k * D + t];
    float s = v * v;
    #pragma unroll
    for (int m = 1; m <= 32; m <<= 1) s += __shfl_xor(s, m);
    __shared__ float ws2[2];
    if ((t & 63) == 0) ws2[t >> 6] = s;
    __syncthreads();
    float total = ws2[0] + ws2[1];
    float n = sqrtf(total);
    float q = v / fmaxf(n, 1e-12f);
    const int kk = t >> 5, quad = (t >> 3) & 3, b = t & 7;
    const int flane = (k & 15) + (quad << 4);
    const int g = k >> 4;
    bws2[(size_t)(g * 2 + (kk >> 1)) * 1024 + flane * 16 + (kk & 1) * 8 + b] =
        (unsigned char)(pk_fp8<false>(q, q, 0u) & 0xFFu);
    if (t == 0) cnorm[k] = n;
}

// ---- Main: 8 autonomous waves share LDS-resident B; one barrier total ----
__global__ __launch_bounds__(512, 1) void cluster_main(
    const float* __restrict__ feats,        // [N][128] fp32
    const unsigned char* __restrict__ bws2, // frag-linear fp8 centers, 128 KB
    const float* __restrict__ cnorm,        // [1024] fp32
    float* __restrict__ wsum) {

    extern __shared__ unsigned char Bs[];    // 131072 B: LDS copy of bws2
    __shared__ float nf_w[8][32];
    __shared__ float bm_w[8][32];

    const int tid  = threadIdx.x;            // 0..511, 8 waves
    const int lane = tid & 63;
    const int w    = tid >> 6;
    const int m16  = lane & 15;
    const int quad = lane >> 4;              // 0..3

    const int gw   = blockIdx.x * 8 + w;     // global wave id = tile id
    const int row0 = gw * 32;

    // ---- Stage all of B: linear 128 KB copy, 16 iters x 512 thr x 16 B ----
    #pragma unroll 4
    for (int i = 0; i < 16; ++i) {
        uint4 v = *(const uint4*)(bws2 + (size_t)i * 8192 + tid * 16);
        *(uint4*)&Bs[i * 8192 + tid * 16] = v;
    }

    // ---- A fragments direct from global (R15-verified) + row sumsq ----
    long long afr[2][4];
    float sq[2];
    #pragma unroll
    for (int i2 = 0; i2 < 2; ++i2) {
        const float* rp = feats + (size_t)(row0 + i2 * 16 + m16) * D + quad * 8;
        float a = 0.0f;
        #pragma unroll
        for (int kk = 0; kk < 4; ++kk) {
            float4 u = *(const float4*)(rp + kk * 32);
            float4 v = *(const float4*)(rp + kk * 32 + 4);
            unsigned int lo = pk_fp8<true>(u.z, u.w, pk_fp8<false>(u.x, u.y, 0u));
            unsigned int hi = pk_fp8<true>(v.z, v.w, pk_fp8<false>(v.x, v.y, 0u));
            afr[i2][kk] = (long long)(((unsigned long long)hi << 32) | (unsigned long long)lo);
            a += u.x*u.x + u.y*u.y + u.z*u.z + u.w*u.w;
            a += v.x*v.x + v.y*v.y + v.z*v.z + v.w*v.w;
        }
        sq[i2] = a;
    }
    #pragma unroll
    for (int i2 = 0; i2 < 2; ++i2) {         // reduce over quads (cols)
        sq[i2] += __shfl_xor(sq[i2], 16);
        sq[i2] += __shfl_xor(sq[i2], 32);
    }
    if (quad == 0) {
        #pragma unroll
        for (int i2 = 0; i2 < 2; ++i2) nf_w[w][i2 * 16 + m16] = sq[i2];
    }

    __syncthreads();                         // Bs fully staged (vmcnt+lgkm drained)

    float best[8];                           // keyed floats, slot = i2*4 + r
    #pragma unroll
    for (int s = 0; s < 8; ++s) best[s] = -3.0e38f;

    const unsigned char* bb = Bs + lane * 16;

    auto loadB = [&](int g2, llx2& x0, llx2& x1, llx2& x2, llx2& x3) {
        const unsigned char* p = bb + (size_t)g2 * 4096;
        x0 = *(const llx2*)(p);              // group 2g2,   kk0/kk1
        x1 = *(const llx2*)(p + 1024);       // group 2g2,   kk2/kk3
        x2 = *(const llx2*)(p + 2048);       // group 2g2+1, kk0/kk1
        x3 = *(const llx2*)(p + 3072);       // group 2g2+1, kk2/kk3
    };
    auto stepB = [&](int g2, llx2 x0, llx2 x1, llx2 x2, llx2 x3) {
        long long br0[4] = { x0[0], x0[1], x1[0], x1[1] };
        long long br1[4] = { x2[0], x2[1], x3[0], x3[1] };
        floatx4 a00 = (floatx4){0.f,0.f,0.f,0.f};
        floatx4 a01 = (floatx4){0.f,0.f,0.f,0.f};
        floatx4 a10 = (floatx4){0.f,0.f,0.f,0.f};
        floatx4 a11 = (floatx4){0.f,0.f,0.f,0.f};
        #pragma unroll
        for (int kk = 0; kk < 4; ++kk) {
            a00 = __builtin_amdgcn_mfma_f32_16x16x32_fp8_fp8(afr[0][kk], br0[kk], a00, 0, 0, 0);
            a01 = __builtin_amdgcn_mfma_f32_16x16x32_fp8_fp8(afr[0][kk], br1[kk], a01, 0, 0, 0);
            a10 = __builtin_amdgcn_mfma_f32_16x16x32_fp8_fp8(afr[1][kk], br0[kk], a10, 0, 0, 0);
            a11 = __builtin_amdgcn_mfma_f32_16x16x32_fp8_fp8(afr[1][kk], br1[kk], a11, 0, 0, 0);
        }
        const unsigned int inv0 = 1023u - (unsigned)(g2 * 32 + m16);
        const unsigned int inv1 = inv0 - 16u;
        #pragma unroll
        for (int r = 0; r < 4; ++r) {
            best[r]     = fmaxf(best[r],
                           fmaxf(key_pack(a00[r], inv0), key_pack(a01[r], inv1)));
            best[4 + r] = fmaxf(best[4 + r],
                           fmaxf(key_pack(a10[r], inv0), key_pack(a11[r], inv1)));
        }
    };

    // ---- sweep all 1024 centers: 32 pair-groups, depth-1 LDS pipeline ----
    llx2 xa0, xa1, xa2, xa3, yb0, yb1, yb2, yb3;
    loadB(0, xa0, xa1, xa2, xa3);
    #pragma unroll 1
    for (int it2 = 0; it2 < 16; ++it2) {
        loadB(2 * it2 + 1, yb0, yb1, yb2, yb3);
        stepB(2 * it2,     xa0, xa1, xa2, xa3);
        if (it2 < 15)
            loadB(2 * it2 + 2, xa0, xa1, xa2, xa3);
        stepB(2 * it2 + 1, yb0, yb1, yb2, yb3);
    }

    // cross-m16 butterfly: per (quad,i2,r) max over all 1024 centers
    #pragma unroll
    for (int mask = 1; mask <= 8; mask <<= 1)
        #pragma unroll
        for (int s = 0; s < 8; ++s)
            best[s] = fmaxf(best[s], __shfl_xor(best[s], mask));

    if (m16 == 0) {
        #pragma unroll
        for (int s = 0; s < 8; ++s) {
            int row = (s >> 2) * 16 + quad * 4 + (s & 3);
            bm_w[w][row] = best[s];
        }
    }
    asm volatile("s_waitcnt lgkmcnt(0)" ::: "memory");  // bm_w wave-visible

    // ---- decode + loss, 32 rows on 32 lanes; wave reduce; one store ----
    float lsum = 0.0f;
    if (lane < 32) {
        const int row = lane;
        unsigned int ub = __builtin_bit_cast(unsigned int, bm_w[w][row]);
        int   ka = 1023 - (int)(ub & 1023u);
        float d  = __builtin_bit_cast(float, (ub & 0xFFFFFC00u) | 0x200u);
        float nf = fmaxf(sqrtf(nf_w[w][row]), 1e-12f);
        float na = cnorm[ka];
        lsum = 1.0f - 2.0f * d * na / nf + na * na;
    }
    #pragma unroll
    for (int m = 1; m <= 32; m <<= 1) lsum += __shfl_xor(lsum, m);
    if (lane == 0) wsum[gw] = lsum;
}

// ---- Final: sum 4096 per-wave partials -> out[0] ----
__global__ void reduce_out(const float* __restrict__ wsum,
                           float* __restrict__ out, int nW, float invN) {
    float s = 0.0f;
    for (int i = threadIdx.x; i < (nW >> 2); i += 256) {
        float4 v = ((const float4*)wsum)[i];
        s += (v.x + v.y) + (v.z + v.w);
    }
    #pragma unroll
    for (int m = 1; m <= 32; m <<= 1) s += __shfl_xor(s, m);
    __shared__ float ws4[4];
    if ((threadIdx.x & 63) == 0) ws4[threadIdx.x >> 6] = s;
    __syncthreads();
    if (threadIdx.x == 0)
        out[0] = ((ws4[0] + ws4[1]) + (ws4[2] + ws4[3])) * invN;
}

extern "C" void kernel_launch(void* const* d_in, const int* in_sizes, int n_in,
                              void* d_out, int out_size, void* d_ws, size_t ws_size,
                              hipStream_t stream) {
    const float* feats   = (const float*)d_in[0];
    const float* centers = (const float*)d_in[1];
    const int N = in_sizes[0] / D;   // 131072
    const int K = in_sizes[1] / D;   // 1024

    unsigned char* bws2 = (unsigned char*)d_ws;                    // 128 KB
    float* cnorm = (float*)((char*)d_ws + (size_t)K * D);          // 4 KB
    float* wsum  = (float*)((char*)d_ws + (size_t)K * D + 4096);   // 16 KB
    float* out = (float*)d_out;

    const int smem = K * D;                  // 131072 B dynamic (~133 KB total)
    (void)hipFuncSetAttribute((const void*)cluster_main,
                              hipFuncAttributeMaxDynamicSharedMemorySize, smem);

    prep_centers<<<K, D, 0, stream>>>(centers, bws2, cnorm);

    const int grid = (N / 32) / 8;           // 512 blocks x 8 waves = 4096 tiles
    cluster_main<<<grid, 512, smem, stream>>>(feats, bws2, cnorm, wsum);

    reduce_out<<<1, 256, 0, stream>>>(wsum, out, grid * 8, 1.0f / (float)N);
}

// Round 13
// 115.838 us; speedup vs baseline: 1.0661x; 1.0661x over previous
//
#include <hip/hip_runtime.h>

// ClusterLoss fused kernel for MI355X (gfx950).  R19.
// Post-mortem R18: B-bandwidth theory REFUTED (LDS-resident B, 0 conflicts,
// 8x less L2 traffic -> SLOWER 48-53us; 2 serialized generations + 2 waves/
// SIMD). Across R14-R18 the achieved MFMA rate plateaus at 716-834 TF ~ 40%
// of fp8 ubench -- the documented "m97-class" plateau. Matching levers from
// the learn_hip catalog: deeper prefetch (cover L2 queuing latency beyond 1
// iteration) and T5 s_setprio around the MFMA cluster (pays on DE-PHASED
// waves -- our autonomous waves, attn-like regime, +4-7% measured there).
// R19 = R17 (best, 41us) + 4-set named-register depth-2 B pipeline (loads
// issue 2 groups ahead; fully unrolled, all indices compile-time -- rule #20)
// + setprio(1) around the 16-MFMA cluster. Geometry unchanged.
// Allocator rules (measured): 1024-thr block or min-waves>=2 pins 64 VGPR.
// Use (256,1). Spill tripwire = WRITE_SIZE.
// loss_n = 1 - 2 d na/nf + na^2 (fp32 scalars).

#define D 128
#define TROWS 32

typedef __attribute__((ext_vector_type(4))) float floatx4;
typedef __attribute__((ext_vector_type(2))) long long llx2;

template <bool HI>
__device__ __forceinline__ unsigned int pk_fp8(float a, float b, unsigned int old) {
    return (unsigned int)__builtin_amdgcn_cvt_pk_fp8_f32(a, b, (int)old, HI);
}

__device__ __forceinline__ float key_pack(float v, unsigned int inv_k) {
    unsigned int u = __builtin_bit_cast(unsigned int, v);
    unsigned int r = (0x3FFu & inv_k) | (~0x3FFu & u);   // v_bfi_b32
    return __builtin_bit_cast(float, r);
}

// ---- Prep: normalize centers -> fp8, scattered into frag-ordered bws ----
// bws byte layout: ((g*64 + lane)*4 + kk)*8 + b  ==  chat[g*16 + (lane&15)]
//                                                    [kk*32 + (lane>>4)*8 + b]
__global__ void prep_centers(const float* __restrict__ centers,
                             unsigned char* __restrict__ bws,
                             float* __restrict__ cnorm) {
    const int k = blockIdx.x;
    const int t = threadIdx.x;            // 128 threads, one per dim
    float v = centers[(size_t)k * D + t];
    float s = v * v;
    #pragma unroll
    for (int m = 1; m <= 32; m <<= 1) s += __shfl_xor(s, m);
    __shared__ float ws2[2];
    if ((t & 63) == 0) ws2[t >> 6] = s;
    __syncthreads();
    float total = ws2[0] + ws2[1];
    float n = sqrtf(total);
    float q = v / fmaxf(n, 1e-12f);
    const int kk = t >> 5, quad = (t >> 3) & 3, b = t & 7;
    const int lane = (k & 15) + (quad << 4);
    const int g = k >> 4;
    bws[(((size_t)g * 64 + lane) * 4 + kk) * 8 + b] =
        (unsigned char)(pk_fp8<false>(q, q, 0u) & 0xFFu);
    if (t == 0) cnorm[k] = n;
}

// ---- Main: 4 waves = 2 tiles x 2 center-halves; two barriers total ----
__global__ __launch_bounds__(256, 1) void cluster_main(
    const float* __restrict__ feats,        // [N][128] fp32
    const unsigned char* __restrict__ bws,  // frag-ordered fp8 centers, 128 KB
    const float* __restrict__ cnorm,        // [1024] fp32
    float* __restrict__ wsum) {

    __shared__ unsigned char As[2][TROWS * D];   // swizzled fp8 A tiles, 8 KB
    __shared__ float nf_l[2][TROWS];
    __shared__ float bm[4][TROWS];

    const int tid  = threadIdx.x;            // 0..255, 4 waves
    const int lane = tid & 63;
    const int w    = tid >> 6;
    const int tt   = w >> 1;                 // tile within block (0,1)
    const int hh   = w & 1;                  // center half (0,1)

    const int m16  = lane & 15;
    const int quad = lane >> 4;              // 0..3
    const int q1   = quad >> 1, q0 = quad & 1;
    const int m8   = m16 & 7;

    // ---- Cooperative A staging: 256 thr = 32 rows x 8 chunks, per tile ----
    const int sr = tid >> 3;                 // row 0..31
    const int sc = tid & 7;                  // 16-float chunk 0..7
    #pragma unroll
    for (int t2 = 0; t2 < 2; ++t2) {
        const int row0 = (blockIdx.x * 2 + t2) * TROWS;
        const float4* src =
            (const float4*)(feats + (size_t)(row0 + sr) * D + sc * 16);
        float4 v0 = src[0], v1 = src[1], v2 = src[2], v3 = src[3];
        uint4 wd;
        wd.x = pk_fp8<true>(v0.z, v0.w, pk_fp8<false>(v0.x, v0.y, 0u));
        wd.y = pk_fp8<true>(v1.z, v1.w, pk_fp8<false>(v1.x, v1.y, 0u));
        wd.z = pk_fp8<true>(v2.z, v2.w, pk_fp8<false>(v2.x, v2.y, 0u));
        wd.w = pk_fp8<true>(v3.z, v3.w, pk_fp8<false>(v3.x, v3.y, 0u));
        *(uint4*)&As[t2][sr * D + ((sc ^ (sr & 7)) << 4)] = wd;
        float a = v0.x*v0.x + v0.y*v0.y + v0.z*v0.z + v0.w*v0.w;
        a += v1.x*v1.x + v1.y*v1.y + v1.z*v1.z + v1.w*v1.w;
        a += v2.x*v2.x + v2.y*v2.y + v2.z*v2.z + v2.w*v2.w;
        a += v3.x*v3.x + v3.y*v3.y + v3.z*v3.z + v3.w*v3.w;
        #pragma unroll
        for (int m = 1; m <= 4; m <<= 1) a += __shfl_xor(a, m);
        if (sc == 0) nf_l[t2][sr] = a;
    }
    __syncthreads();                         // As + nf_l visible block-wide

    // ---- A fragments (rows i2*16+m16 of tile tt) ----
    long long afr[2][4];
    #pragma unroll
    for (int i2 = 0; i2 < 2; ++i2) {
        const int r = i2 * 16 + m16;
        #pragma unroll
        for (int kk = 0; kk < 4; ++kk) {
            int pc = (2 * kk + q1) ^ m8;
            afr[i2][kk] = *(const long long*)&As[tt][r * D + pc * 16 + q0 * 8];
        }
    }

    float best[8];                           // keyed floats, slot = i2*4 + r
    #pragma unroll
    for (int s = 0; s < 8; ++s) best[s] = -3.0e38f;

    const unsigned char* bbase = bws + (size_t)hh * 65536 + (size_t)lane * 32;

// load pair-group i's 4 dwordx4 into a named set
#define LOADB(i, s0, s1, s2, s3) do {                                   \
    const unsigned char* p_ = bbase + (size_t)(i) * 4096;               \
    s0 = *(const llx2*)(p_);                                            \
    s1 = *(const llx2*)(p_ + 16);                                       \
    s2 = *(const llx2*)(p_ + 2048);                                     \
    s3 = *(const llx2*)(p_ + 2064); } while (0)

// consume pair-group g2 from a named set; setprio(1) around MFMA cluster
#define STEPB(g2, x0, x1, x2, x3) do {                                  \
    long long br0_[4] = { x0[0], x0[1], x1[0], x1[1] };                 \
    long long br1_[4] = { x2[0], x2[1], x3[0], x3[1] };                 \
    floatx4 a00 = (floatx4){0.f,0.f,0.f,0.f};                           \
    floatx4 a01 = (floatx4){0.f,0.f,0.f,0.f};                           \
    floatx4 a10 = (floatx4){0.f,0.f,0.f,0.f};                           \
    floatx4 a11 = (floatx4){0.f,0.f,0.f,0.f};                           \
    __builtin_amdgcn_s_setprio(1);                                      \
    _Pragma("unroll")                                                   \
    for (int kk = 0; kk < 4; ++kk) {                                    \
        a00 = __builtin_amdgcn_mfma_f32_16x16x32_fp8_fp8(afr[0][kk], br0_[kk], a00, 0, 0, 0); \
        a01 = __builtin_amdgcn_mfma_f32_16x16x32_fp8_fp8(afr[0][kk], br1_[kk], a01, 0, 0, 0); \
        a10 = __builtin_amdgcn_mfma_f32_16x16x32_fp8_fp8(afr[1][kk], br0_[kk], a10, 0, 0, 0); \
        a11 = __builtin_amdgcn_mfma_f32_16x16x32_fp8_fp8(afr[1][kk], br1_[kk], a11, 0, 0, 0); \
    }                                                                   \
    __builtin_amdgcn_s_setprio(0);                                      \
    const unsigned int inv0_ = 1023u - (unsigned)(hh * 512 + (g2) * 32 + m16); \
    const unsigned int inv1_ = inv0_ - 16u;                             \
    _Pragma("unroll")                                                   \
    for (int r = 0; r < 4; ++r) {                                       \
        best[r]     = fmaxf(best[r],                                    \
                       fmaxf(key_pack(a00[r], inv0_), key_pack(a01[r], inv1_))); \
        best[4 + r] = fmaxf(best[4 + r],                                \
                       fmaxf(key_pack(a10[r], inv0_), key_pack(a11[r], inv1_))); \
    } } while (0)

    // ---- sweep 512 centers: 16 pair-groups, depth-2, 4 named sets ----
    llx2 A0,A1,A2,A3, B0,B1,B2,B3, C0,C1,C2,C3, E0,E1,E2,E3;
    LOADB(0,  A0,A1,A2,A3);
    LOADB(1,  B0,B1,B2,B3);
    LOADB(2,  C0,C1,C2,C3);  STEPB(0,  A0,A1,A2,A3);
    LOADB(3,  E0,E1,E2,E3);  STEPB(1,  B0,B1,B2,B3);
    LOADB(4,  A0,A1,A2,A3);  STEPB(2,  C0,C1,C2,C3);
    LOADB(5,  B0,B1,B2,B3);  STEPB(3,  E0,E1,E2,E3);
    LOADB(6,  C0,C1,C2,C3);  STEPB(4,  A0,A1,A2,A3);
    LOADB(7,  E0,E1,E2,E3);  STEPB(5,  B0,B1,B2,B3);
    LOADB(8,  A0,A1,A2,A3);  STEPB(6,  C0,C1,C2,C3);
    LOADB(9,  B0,B1,B2,B3);  STEPB(7,  E0,E1,E2,E3);
    LOADB(10, C0,C1,C2,C3);  STEPB(8,  A0,A1,A2,A3);
    LOADB(11, E0,E1,E2,E3);  STEPB(9,  B0,B1,B2,B3);
    LOADB(12, A0,A1,A2,A3);  STEPB(10, C0,C1,C2,C3);
    LOADB(13, B0,B1,B2,B3);  STEPB(11, E0,E1,E2,E3);
    LOADB(14, C0,C1,C2,C3);  STEPB(12, A0,A1,A2,A3);
    LOADB(15, E0,E1,E2,E3);  STEPB(13, B0,B1,B2,B3);
    STEPB(14, C0,C1,C2,C3);
    STEPB(15, E0,E1,E2,E3);

#undef LOADB
#undef STEPB

    // cross-m16 butterfly: per (quad,i2,r) max over this wave's centers
    #pragma unroll
    for (int mask = 1; mask <= 8; mask <<= 1)
        #pragma unroll
        for (int s = 0; s < 8; ++s)
            best[s] = fmaxf(best[s], __shfl_xor(best[s], mask));

    if (m16 == 0) {
        #pragma unroll
        for (int s = 0; s < 8; ++s) {
            int row = (s >> 2) * 16 + quad * 4 + (s & 3);
            bm[w][row] = best[s];
        }
    }
    __syncthreads();                         // bm visible block-wide

    // ---- combine halves; decode; loss; reduce (even waves only) ----
    float lsum = 0.0f;
    if (hh == 0 && lane < 32) {
        const int row = lane;                // 32 rows on 32 lanes
        float kmax = fmaxf(bm[w][row], bm[w + 1][row]);
        unsigned int ub = __builtin_bit_cast(unsigned int, kmax);
        int   ka = 1023 - (int)(ub & 1023u);
        float d  = __builtin_bit_cast(float, (ub & 0xFFFFFC00u) | 0x200u);
        float nf = fmaxf(sqrtf(nf_l[tt][row]), 1e-12f);
        float na = cnorm[ka];
        lsum = 1.0f - 2.0f * d * na / nf + na * na;
    }
    #pragma unroll
    for (int m = 1; m <= 16; m <<= 1) lsum += __shfl_xor(lsum, m);
    if (hh == 0 && lane == 0) wsum[blockIdx.x * 2 + tt] = lsum;
}

// ---- Final: sum 4096 per-tile partials -> out[0] ----
__global__ void reduce_out(const float* __restrict__ wsum,
                           float* __restrict__ out, int nW, float invN) {
    float s = 0.0f;
    for (int i = threadIdx.x; i < (nW >> 2); i += 256) {
        float4 v = ((const float4*)wsum)[i];
        s += (v.x + v.y) + (v.z + v.w);
    }
    #pragma unroll
    for (int m = 1; m <= 32; m <<= 1) s += __shfl_xor(s, m);
    __shared__ float ws4[4];
    if ((threadIdx.x & 63) == 0) ws4[threadIdx.x >> 6] = s;
    __syncthreads();
    if (threadIdx.x == 0)
        out[0] = ((ws4[0] + ws4[1]) + (ws4[2] + ws4[3])) * invN;
}

extern "C" void kernel_launch(void* const* d_in, const int* in_sizes, int n_in,
                              void* d_out, int out_size, void* d_ws, size_t ws_size,
                              hipStream_t stream) {
    const float* feats   = (const float*)d_in[0];
    const float* centers = (const float*)d_in[1];
    const int N = in_sizes[0] / D;   // 131072
    const int K = in_sizes[1] / D;   // 1024

    unsigned char* bws = (unsigned char*)d_ws;                     // 128 KB
    float* cnorm = (float*)((char*)d_ws + (size_t)K * D);          // 4 KB
    float* wsum  = (float*)((char*)d_ws + (size_t)K * D + 4096);   // 16 KB
    float* out = (float*)d_out;

    prep_centers<<<K, D, 0, stream>>>(centers, bws, cnorm);

    const int grid = (N / TROWS) / 2;        // 2048 blocks: 2 tiles x 2 halves
    cluster_main<<<grid, 256, 0, stream>>>(feats, bws, cnorm, wsum);

    reduce_out<<<1, 256, 0, stream>>>(wsum, out, grid * 2, 1.0f / (float)N);
}